// Round 5
// baseline (449.330 us; speedup 1.0000x reference)
//
#include <hip/hip_runtime.h>
#include <hip/hip_bf16.h>
#include <math.h>

#define B_   256
#define NPG_ 200
#define N0_  (B_*NPG_)     // 51200
#define DEGC 16
#define E_   (N0_*DEGC)    // 819200
#define SLOTG (NPG_*DEGC)  // 3200 edge slots per graph (fixed at every stage)
#define CSTRIDE 4096       // padded CSR slots per graph (>= 3200 + 3*200)
#define CSRN (B_*CSTRIDE)  // 1048576
#define FIN_ 128
#define H_   256
#define K1_  100
#define K2_  50
#define K3_  25

// bijective XCD-chunk swizzle (m204): dispatch round-robins block i -> XCD i%8;
// remap so XCD x owns a contiguous chunk of logical ids.
__device__ __forceinline__ int xcd_swz(int bid, int nwg) {
    int q = nwg >> 3, r = nwg & 7;
    int x = bid & 7, j = bid >> 3;
    return (x < r ? x * (q + 1) : r * (q + 1) + (x - r) * q) + j;
}

// ---------------- init: copy edges, em=1 ----------------
__global__ void init_edges_k(const int* __restrict__ es, const int* __restrict__ ed,
                             int* __restrict__ src, int* __restrict__ dst,
                             float* __restrict__ em) {
    int e = blockIdx.x * 256 + threadIdx.x;
    if (e < E_) { src[e] = es[e]; dst[e] = ed[e]; em[e] = 1.0f; }
}

// ---------------- gemm128: C[n x FO] = A[n x K] @ W[K x FO], 128x128 tile ----------------
__global__ __launch_bounds__(256) void gemm128(const float* __restrict__ A, const float* __restrict__ W,
                        float* __restrict__ C, int n, int K, int FO) {
    __shared__ float As[16][132];
    __shared__ float Bs[16][132];
    int t = threadIdx.x;
    int tx = t & 15, ty = t >> 4;
    int bm = xcd_swz(blockIdx.x, gridDim.x) * 128, bn = blockIdx.y * 128;
    int ar = t >> 1, akq = (t & 1) * 8;
    int bkk = t >> 4, bn0 = (t & 15) * 8;
    float acc[8][8] = {};
    for (int k0 = 0; k0 < K; k0 += 16) {
        float4 a0 = *(const float4*)&A[(size_t)(bm + ar) * K + k0 + akq];
        float4 a1 = *(const float4*)&A[(size_t)(bm + ar) * K + k0 + akq + 4];
        As[akq + 0][ar] = a0.x; As[akq + 1][ar] = a0.y; As[akq + 2][ar] = a0.z; As[akq + 3][ar] = a0.w;
        As[akq + 4][ar] = a1.x; As[akq + 5][ar] = a1.y; As[akq + 6][ar] = a1.z; As[akq + 7][ar] = a1.w;
        *(float4*)&Bs[bkk][bn0]     = *(const float4*)&W[(size_t)(k0 + bkk) * FO + bn + bn0];
        *(float4*)&Bs[bkk][bn0 + 4] = *(const float4*)&W[(size_t)(k0 + bkk) * FO + bn + bn0 + 4];
        __syncthreads();
        #pragma unroll
        for (int kk = 0; kk < 16; kk++) {
            float4 av0 = *(float4*)&As[kk][ty * 8];
            float4 av1 = *(float4*)&As[kk][ty * 8 + 4];
            float4 bv0 = *(float4*)&Bs[kk][tx * 8];
            float4 bv1 = *(float4*)&Bs[kk][tx * 8 + 4];
            float a[8] = {av0.x, av0.y, av0.z, av0.w, av1.x, av1.y, av1.z, av1.w};
            float b[8] = {bv0.x, bv0.y, bv0.z, bv0.w, bv1.x, bv1.y, bv1.z, bv1.w};
            #pragma unroll
            for (int i = 0; i < 8; i++)
                #pragma unroll
                for (int j = 0; j < 8; j++) acc[i][j] += a[i] * b[j];
        }
        __syncthreads();
    }
    #pragma unroll
    for (int i = 0; i < 8; i++) {
        float4 c0 = {acc[i][0], acc[i][1], acc[i][2], acc[i][3]};
        float4 c1 = {acc[i][4], acc[i][5], acc[i][6], acc[i][7]};
        *(float4*)&C[(size_t)(bm + ty * 8 + i) * FO + bn + tx * 8]     = c0;
        *(float4*)&C[(size_t)(bm + ty * 8 + i) * FO + bn + tx * 8 + 4] = c1;
    }
}

// ---------------- gemm64 (bias+relu) for MLP layers ----------------
__global__ void gemm64(const float* __restrict__ A, const float* __restrict__ W,
                       const float* __restrict__ bias, float* __restrict__ C,
                       int n, int K, int FO, int relu) {
    __shared__ float As[16][65];
    __shared__ float Bs[16][65];
    int tid = threadIdx.x;
    int tx = tid & 15, ty = tid >> 4;
    int bm = blockIdx.x * 64, bn = blockIdx.y * 64;
    float acc[4][4] = {};
    for (int k0 = 0; k0 < K; k0 += 16) {
        #pragma unroll
        for (int i = 0; i < 4; i++) {
            int lin = i * 256 + tid;
            int r = lin >> 4, kk = lin & 15;
            As[kk][r] = A[(size_t)(bm + r) * K + k0 + kk];
        }
        #pragma unroll
        for (int i = 0; i < 4; i++) {
            int lin = i * 256 + tid;
            int nn = lin & 63, kk = lin >> 6;
            Bs[kk][nn] = W[(size_t)(k0 + kk) * FO + bn + nn];
        }
        __syncthreads();
        #pragma unroll
        for (int kk = 0; kk < 16; kk++) {
            float a[4], b[4];
            #pragma unroll
            for (int i = 0; i < 4; i++) a[i] = As[kk][ty * 4 + i];
            #pragma unroll
            for (int j = 0; j < 4; j++) b[j] = Bs[kk][tx * 4 + j];
            #pragma unroll
            for (int i = 0; i < 4; i++)
                #pragma unroll
                for (int j = 0; j < 4; j++) acc[i][j] += a[i] * b[j];
        }
        __syncthreads();
    }
    for (int i = 0; i < 4; i++)
        for (int j = 0; j < 4; j++) {
            float v = acc[i][j] + bias[bn + tx * 4 + j];
            if (relu) v = fmaxf(v, 0.0f);
            C[(size_t)(bm + ty * 4 + i) * FO + bn + tx * 4 + j] = v;
        }
}

// ---------------- per-graph CSR build (padded to 4 slots, coef precomputed) --------
// Edges for graph g ALWAYS live at slots [g*SLOTG, (g+1)*SLOTG) regardless of stage;
// em masks dead edges. CSR output for graph g goes to [g*CSTRIDE, ...).
// Per-node slot range [offs, offe) is padded to a multiple of 4; padding slots
// reference the node itself with coef 0.
__global__ void csr_build_k(const int* __restrict__ src, const int* __restrict__ dst,
                            const float* __restrict__ em, int* __restrict__ offs,
                            int* __restrict__ offe, int* __restrict__ csrc,
                            float* __restrict__ coef, float* __restrict__ dinv, int npg) {
    __shared__ int   cnt[256];
    __shared__ int   sc[256];
    __shared__ int   pos[256];
    __shared__ float dv[256];
    int g = xcd_swz(blockIdx.x, B_);
    int t = threadIdx.x;
    int ebase = g * SLOTG;
    int nb0 = g * npg;
    int cbase = g * CSTRIDE;
    cnt[t] = 0;
    __syncthreads();
    for (int e = ebase + t; e < ebase + SLOTG; e += 256)
        if (em[e] > 0.5f) atomicAdd(&cnt[dst[e] - nb0], 1);
    __syncthreads();
    int v = (t < npg) ? cnt[t] : 0;
    float dloc = rsqrtf((float)v + 1.0f);
    dv[t] = dloc;
    int vp = (v + 3) & ~3;
    sc[t] = vp; __syncthreads();
    for (int d = 1; d < 256; d <<= 1) {
        int u = (t >= d) ? sc[t - d] : 0;
        __syncthreads();
        sc[t] += u;
        __syncthreads();
    }
    int excl = sc[t] - vp;
    pos[t] = cbase + excl;
    if (t < npg) {
        offs[nb0 + t] = cbase + excl;
        offe[nb0 + t] = cbase + excl + vp;
        dinv[nb0 + t] = dloc;
        for (int p = v; p < vp; p++) {       // padding: self with zero coef
            csrc[cbase + excl + p] = nb0 + t;
            coef[cbase + excl + p] = 0.0f;
        }
    }
    __syncthreads();
    for (int e = ebase + t; e < ebase + SLOTG; e += 256)
        if (em[e] > 0.5f) {
            int dl = dst[e] - nb0;
            int p = atomicAdd(&pos[dl], 1);
            csrc[p] = src[e];
            coef[p] = dv[dl] * dv[src[e] - nb0];
        }
}

// ------- GCN aggregation (wave/node, 4 rows in flight) + fused score dot xs=h.Ws -------
__global__ void agg_gcn_k(const float* __restrict__ xw, const int* __restrict__ offs,
                          const int* __restrict__ offe, const int* __restrict__ csrc,
                          const float* __restrict__ coef, const float* __restrict__ dinv,
                          const float* __restrict__ bias, const float* __restrict__ Ws,
                          float* __restrict__ out, float* __restrict__ xs, int n) {
    int node = xcd_swz(blockIdx.x, gridDim.x) * 4 + (threadIdx.x >> 6);
    int lane = threadIdx.x & 63;
    const float4* xw4 = (const float4*)xw;
    float dd = dinv[node];
    float4 acc = {0.f, 0.f, 0.f, 0.f};
    int e0 = offs[node], e1 = offe[node];
    for (int j = e0; j < e1; j += 4) {
        int4   s4 = *(const int4*)&csrc[j];
        float4 c4 = *(const float4*)&coef[j];
        float4 v0 = xw4[(size_t)s4.x * 64 + lane];
        float4 v1 = xw4[(size_t)s4.y * 64 + lane];
        float4 v2 = xw4[(size_t)s4.z * 64 + lane];
        float4 v3 = xw4[(size_t)s4.w * 64 + lane];
        acc.x += c4.x * v0.x + c4.y * v1.x + c4.z * v2.x + c4.w * v3.x;
        acc.y += c4.x * v0.y + c4.y * v1.y + c4.z * v2.y + c4.w * v3.y;
        acc.z += c4.x * v0.z + c4.y * v1.z + c4.z * v2.z + c4.w * v3.z;
        acc.w += c4.x * v0.w + c4.y * v1.w + c4.z * v2.w + c4.w * v3.w;
    }
    float4 self = xw4[(size_t)node * 64 + lane];
    float scf = dd * dd;
    float4 r;
    r.x = fmaxf(acc.x + self.x * scf + bias[lane * 4 + 0], 0.f);
    r.y = fmaxf(acc.y + self.y * scf + bias[lane * 4 + 1], 0.f);
    r.z = fmaxf(acc.z + self.z * scf + bias[lane * 4 + 2], 0.f);
    r.w = fmaxf(acc.w + self.w * scf + bias[lane * 4 + 3], 0.f);
    ((float4*)out)[(size_t)node * 64 + lane] = r;
    // fused: xs[node] = h[node,:] . Ws
    float p = r.x * Ws[lane * 4 + 0] + r.y * Ws[lane * 4 + 1] +
              r.z * Ws[lane * 4 + 2] + r.w * Ws[lane * 4 + 3];
    #pragma unroll
    for (int d = 32; d > 0; d >>= 1) p += __shfl_down(p, d);
    if (lane == 0) xs[node] = p;
}

// -------- fused score GCN + top-k + pool + readout: one block per graph --------
__global__ void score_topk_pool_k(const float* __restrict__ h, const float* __restrict__ xs,
                                  const int* __restrict__ offs, const int* __restrict__ offe,
                                  const int* __restrict__ csrc, const float* __restrict__ coef,
                                  const float* __restrict__ dinv, const float* __restrict__ bs,
                                  int* __restrict__ remap, float* __restrict__ ph,
                                  float* __restrict__ z, int npg, int k, int accumulate) {
    __shared__ float xsl[256];
    __shared__ float sc[256];
    __shared__ int   id[256];
    __shared__ int   ps[128];
    __shared__ float ts[128];
    int g = xcd_swz(blockIdx.x, B_);
    int t = threadIdx.x;
    int nb0 = g * npg;
    xsl[t] = (t < npg) ? xs[nb0 + t] : 0.f;
    __syncthreads();
    float scv = -INFINITY;
    if (t < npg) {
        int gi = nb0 + t;
        float dd = dinv[gi];
        float acc = 0.f;
        for (int j = offs[gi]; j < offe[gi]; j++)   // padding coef==0 -> no-op
            acc += coef[j] * xsl[csrc[j] - nb0];
        scv = acc + xsl[t] * dd * dd + bs[0];
        remap[gi] = -1;
    }
    sc[t] = scv;
    id[t] = (t < npg) ? t : 0x7fffffff;
    __syncthreads();
    for (int ksz = 2; ksz <= 256; ksz <<= 1) {
        for (int j = ksz >> 1; j > 0; j >>= 1) {
            int ixj = t ^ j;
            if (ixj > t) {
                float s1 = sc[t], s2 = sc[ixj];
                int i1 = id[t], i2 = id[ixj];
                bool asc = ((t & ksz) == 0);
                bool agtb = (s1 < s2) || (s1 == s2 && i1 > i2);
                if (asc ? agtb : !agtb) { sc[t] = s2; sc[ixj] = s1; id[t] = i2; id[ixj] = i1; }
            }
            __syncthreads();
        }
    }
    if (t < k) {
        remap[nb0 + id[t]] = g * k + t;
        ps[t] = nb0 + id[t];
        ts[t] = tanhf(sc[t]);
    }
    __syncthreads();
    float mx = -INFINITY, sm = 0.f;
    for (int j = 0; j < k; j++) {
        float v = h[(size_t)ps[j] * H_ + t] * ts[j];
        ph[(size_t)(g * k + j) * H_ + t] = v;
        mx = fmaxf(mx, v); sm += v;
    }
    float mean = sm / (float)k;
    if (accumulate) { z[g * 512 + t] += mx; z[g * 512 + 256 + t] += mean; }
    else            { z[g * 512 + t]  = mx; z[g * 512 + 256 + t]  = mean; }
}

// ---------------- edge remap ----------------
__global__ void edge_remap_k(int* __restrict__ src, int* __restrict__ dst,
                             float* __restrict__ em, const int* __restrict__ remap) {
    int e = blockIdx.x * 256 + threadIdx.x; if (e >= E_) return;
    int ns = remap[src[e]], nd = remap[dst[e]];
    float v = em[e];
    em[e] = (v > 0.5f && ns >= 0 && nd >= 0) ? 1.0f : 0.0f;
    src[e] = ns < 0 ? 0 : ns;
    dst[e] = nd < 0 ? 0 : nd;
}

// ---------------- fused MLP layer-3 + log_softmax ----------------
__global__ void mlp3_lsm_k(const float* __restrict__ A, const float* __restrict__ W,
                           const float* __restrict__ bias, float* __restrict__ out) {
    int m = blockIdx.x, l = threadIdx.x;   // 64 lanes, K=128
    float a0 = A[m * 128 + l], a1 = A[m * 128 + 64 + l];
    float r[10];
    #pragma unroll
    for (int n = 0; n < 10; n++) r[n] = a0 * W[l * 10 + n] + a1 * W[(l + 64) * 10 + n];
    #pragma unroll
    for (int d = 1; d < 64; d <<= 1)
        #pragma unroll
        for (int n = 0; n < 10; n++) r[n] += __shfl_xor(r[n], d);
    float v[10]; float mx = -INFINITY;
    #pragma unroll
    for (int n = 0; n < 10; n++) { v[n] = r[n] + bias[n]; mx = fmaxf(mx, v[n]); }
    float s = 0.f;
    #pragma unroll
    for (int n = 0; n < 10; n++) s += expf(v[n] - mx);
    float ls = logf(s);
    if (l < 10) out[m * 10 + l] = v[l] - mx - ls;
}

extern "C" void kernel_launch(void* const* d_in, const int* in_sizes, int n_in,
                              void* d_out, int out_size, void* d_ws, size_t ws_size,
                              hipStream_t stream) {
    const float* x   = (const float*)d_in[0];
    const int*  esrc = (const int*) d_in[1];
    const int*  edst = (const int*) d_in[2];
    const float *W1 = (const float*)d_in[3],  *b1 = (const float*)d_in[4];
    const float *Ws1= (const float*)d_in[5],  *bs1= (const float*)d_in[6];
    const float *W2 = (const float*)d_in[7],  *b2 = (const float*)d_in[8];
    const float *Ws2= (const float*)d_in[9],  *bs2= (const float*)d_in[10];
    const float *W3 = (const float*)d_in[11], *b3 = (const float*)d_in[12];
    const float *Ws3= (const float*)d_in[13], *bs3= (const float*)d_in[14];
    const float *Wl1= (const float*)d_in[15], *bl1= (const float*)d_in[16];
    const float *Wl2= (const float*)d_in[17], *bl2= (const float*)d_in[18];
    const float *Wl3= (const float*)d_in[19], *bl3= (const float*)d_in[20];
    float* out = (float*)d_out;

    // ---- workspace layout ----
    float* ws = (float*)d_ws;
    float* XW   = ws;                        // N0*H
    float* Hb   = XW + (size_t)N0_ * H_;     // N0*H
    float* PH   = Hb + (size_t)N0_ * H_;     // (B*K1)*H
    float* DINV = PH + (size_t)B_ * K1_ * H_;// N0
    float* XS   = DINV + N0_;                // N0
    float* EMF  = XS + N0_;                  // E
    int*   SRC  = (int*)(EMF + E_);          // E
    int*   DST  = SRC + E_;                  // E
    int*   OFFS = DST + E_;                  // N0
    int*   OFFE = OFFS + N0_;                // N0
    int*   CSRC = OFFE + N0_;                // CSRN
    float* COEF = (float*)(CSRC + CSRN);     // CSRN
    int*   REMAP= (int*)(COEF + CSRN);       // N0
    float* Z    = (float*)(REMAP + N0_);     // B*512
    float* Z1   = Z + B_ * 512;              // B*256
    float* Z2   = Z1 + B_ * 256;             // B*128

    const int EB = E_ / 256;   // 3200

    init_edges_k<<<EB, 256, 0, stream>>>(esrc, edst, SRC, DST, EMF);

    const int nodes[4] = { N0_, B_ * K1_, B_ * K2_, B_ * K3_ };
    const int npgs[3]  = { NPG_, K1_, K2_ };
    const int ks[3]    = { K1_, K2_, K3_ };
    const float* Wm[3]  = { W1, W2, W3 };
    const float* bm[3]  = { b1, b2, b3 };
    const float* Wsm[3] = { Ws1, Ws2, Ws3 };
    const float* bsm[3] = { bs1, bs2, bs3 };

    for (int st = 0; st < 3; st++) {
        int n = nodes[st];
        int npg = npgs[st], k = ks[st];

        // 1. xw = X @ W (128x128-tiled, row panels XCD-chunked)
        if (st == 0)
            gemm128<<<dim3(n / 128, H_ / 128), 256, 0, stream>>>(x, Wm[st], XW, n, FIN_, H_);
        else
            gemm128<<<dim3(n / 128, H_ / 128), 256, 0, stream>>>(PH, Wm[st], XW, n, H_, H_);

        // 2. per-graph padded CSR build (+ per-edge coef)
        csr_build_k<<<B_, 256, 0, stream>>>(SRC, DST, EMF, OFFS, OFFE, CSRC, COEF, DINV, npg);

        // 3. h = relu(agg + self + b), fused xs = h.Ws
        agg_gcn_k<<<n / 4, 256, 0, stream>>>(XW, OFFS, OFFE, CSRC, COEF, DINV, bm[st], Wsm[st], Hb, XS, n);

        // 4-7. score GCN + top-k + pool + readout (one block/graph)
        score_topk_pool_k<<<B_, 256, 0, stream>>>(Hb, XS, OFFS, OFFE, CSRC, COEF, DINV, bsm[st],
                                                  REMAP, PH, Z, npg, k, st > 0 ? 1 : 0);

        // 8. remap edges for next stage
        if (st < 2)
            edge_remap_k<<<EB, 256, 0, stream>>>(SRC, DST, EMF, REMAP);
    }

    // ---- MLP head ----
    gemm64<<<dim3(B_ / 64, 256 / 64), 256, 0, stream>>>(Z,  Wl1, bl1, Z1, B_, 512, 256, 1);
    gemm64<<<dim3(B_ / 64, 128 / 64), 256, 0, stream>>>(Z1, Wl2, bl2, Z2, B_, 256, 128, 1);
    mlp3_lsm_k<<<B_, 64, 0, stream>>>(Z2, Wl3, bl3, out);
}

// Round 6
// 340.316 us; speedup vs baseline: 1.3203x; 1.3203x over previous
//
#include <hip/hip_runtime.h>
#include <hip/hip_bf16.h>
#include <math.h>

#define B_   256
#define NPG_ 200
#define N0_  (B_*NPG_)     // 51200
#define DEGC 16
#define E_   (N0_*DEGC)    // 819200
#define SLOTG (NPG_*DEGC)  // 3200 edge slots per graph (original layout, never moved)
#define CSTRIDE 4096       // padded CSR slots per graph
#define CSRN (B_*CSTRIDE)
#define FIN_ 128
#define H_   256
#define K1_  100
#define K2_  50
#define K3_  25

// bijective XCD-chunk swizzle (m204)
__device__ __forceinline__ int xcd_swz(int bid, int nwg) {
    int q = nwg >> 3, r = nwg & 7;
    int x = bid & 7, j = bid >> 3;
    return (x < r ? x * (q + 1) : r * (q + 1) + (x - r) * q) + j;
}

__global__ void init_curmap_k(int* __restrict__ cm) {
    int i = blockIdx.x * 256 + threadIdx.x;
    if (i < N0_) cm[i] = i;
}

// ---------------- gemm_t: C[M x N] = A[M x K] @ W[K x N] (+bias/relu) ----------------
// BM=BN=64, BK=32, 256 threads, 4x4 per thread. LDS bank-clean (see round-6 notes).
__global__ __launch_bounds__(256) void gemm_t(const float* __restrict__ A, const float* __restrict__ W,
                                              const float* __restrict__ bias, float* __restrict__ C,
                                              int M, int K, int N, int relu) {
    __shared__ float As[32][68];   // transposed: As[k][m]
    __shared__ float Bs[32][68];   // Bs[k][n]
    int t = threadIdx.x;
    int tx = t & 15, ty = t >> 4;
    int bm = xcd_swz(blockIdx.x, gridDim.x) * 64, bn = blockIdx.y * 64;
    int arow = t >> 2, akq = (t & 3) * 8;   // A staging: row 0..63, k-offset {0,8,16,24}
    int brow = t >> 3, bnq = (t & 7) * 8;   // B staging: k 0..31, n-offset {0..56}
    float acc[4][4] = {};
    for (int k0 = 0; k0 < K; k0 += 32) {
        float4 a0 = *(const float4*)&A[(size_t)(bm + arow) * K + k0 + akq];
        float4 a1 = *(const float4*)&A[(size_t)(bm + arow) * K + k0 + akq + 4];
        float4 b0 = *(const float4*)&W[(size_t)(k0 + brow) * N + bn + bnq];
        float4 b1 = *(const float4*)&W[(size_t)(k0 + brow) * N + bn + bnq + 4];
        As[akq + 0][arow] = a0.x; As[akq + 1][arow] = a0.y;
        As[akq + 2][arow] = a0.z; As[akq + 3][arow] = a0.w;
        As[akq + 4][arow] = a1.x; As[akq + 5][arow] = a1.y;
        As[akq + 6][arow] = a1.z; As[akq + 7][arow] = a1.w;
        *(float4*)&Bs[brow][bnq]     = b0;
        *(float4*)&Bs[brow][bnq + 4] = b1;
        __syncthreads();
        #pragma unroll
        for (int kk = 0; kk < 32; kk++) {
            float4 av = *(float4*)&As[kk][ty * 4];
            float4 bv = *(float4*)&Bs[kk][tx * 4];
            float a[4] = {av.x, av.y, av.z, av.w};
            float b[4] = {bv.x, bv.y, bv.z, bv.w};
            #pragma unroll
            for (int i = 0; i < 4; i++)
                #pragma unroll
                for (int j = 0; j < 4; j++) acc[i][j] += a[i] * b[j];
        }
        __syncthreads();
    }
    float bb[4] = {0.f, 0.f, 0.f, 0.f};
    if (bias) {
        #pragma unroll
        for (int j = 0; j < 4; j++) bb[j] = bias[bn + tx * 4 + j];
    }
    #pragma unroll
    for (int i = 0; i < 4; i++) {
        float4 c;
        c.x = acc[i][0] + bb[0]; c.y = acc[i][1] + bb[1];
        c.z = acc[i][2] + bb[2]; c.w = acc[i][3] + bb[3];
        if (relu) {
            c.x = fmaxf(c.x, 0.f); c.y = fmaxf(c.y, 0.f);
            c.z = fmaxf(c.z, 0.f); c.w = fmaxf(c.w, 0.f);
        }
        *(float4*)&C[(size_t)(bm + ty * 4 + i) * N + bn + tx * 4] = c;
    }
}

// -------- per-graph CSR build via CURMAP (edges never rewritten) --------
// Edge slots for graph g: [g*SLOTG,(g+1)*SLOTG) in the ORIGINAL esrc/edst.
// curmap: original node id -> current id (or -1 if pooled away).
// Output CSR padded per node to multiple of 4; padding = self with coef 0.
__global__ void csr_build_k(const int* __restrict__ esrc, const int* __restrict__ edst,
                            const int* __restrict__ curmap, int* __restrict__ offs,
                            int* __restrict__ offe, int* __restrict__ csrc,
                            float* __restrict__ coef, float* __restrict__ dinv, int npg) {
    __shared__ int   cml[256];      // curmap slice (orig-local -> cur-global or -1)
    __shared__ int   cnt[256];
    __shared__ int   sc[256];
    __shared__ int   pos[256];
    __shared__ float dv[256];
    __shared__ int   ecache[SLOTG]; // packed cs_l | cd_l<<8, or -1
    int g = xcd_swz(blockIdx.x, B_);
    int t = threadIdx.x;
    int ebase = g * SLOTG;
    int ob0 = g * NPG_;             // original node base
    int nb0 = g * npg;              // current node base
    int cbase = g * CSTRIDE;
    cml[t] = (t < NPG_) ? curmap[ob0 + t] : -1;
    cnt[t] = 0;
    __syncthreads();
    for (int e = t; e < SLOTG; e += 256) {
        int cs = cml[esrc[ebase + e] - ob0];
        int cd = cml[edst[ebase + e] - ob0];
        int pk = -1;
        if (cs >= 0 && cd >= 0) {
            int cs_l = cs - nb0, cd_l = cd - nb0;
            pk = cs_l | (cd_l << 8);
            atomicAdd(&cnt[cd_l], 1);
        }
        ecache[e] = pk;
    }
    __syncthreads();
    int v = (t < npg) ? cnt[t] : 0;
    float dloc = rsqrtf((float)v + 1.0f);
    dv[t] = dloc;
    int vp = (v + 3) & ~3;
    sc[t] = vp; __syncthreads();
    for (int d = 1; d < 256; d <<= 1) {
        int u = (t >= d) ? sc[t - d] : 0;
        __syncthreads();
        sc[t] += u;
        __syncthreads();
    }
    int excl = sc[t] - vp;
    pos[t] = cbase + excl;
    if (t < npg) {
        offs[nb0 + t] = cbase + excl;
        offe[nb0 + t] = cbase + excl + vp;
        dinv[nb0 + t] = dloc;
        for (int p = v; p < vp; p++) {      // padding: self, zero coef
            csrc[cbase + excl + p] = nb0 + t;
            coef[cbase + excl + p] = 0.0f;
        }
    }
    __syncthreads();
    for (int e = t; e < SLOTG; e += 256) {
        int pk = ecache[e];
        if (pk >= 0) {
            int cs_l = pk & 255, cd_l = pk >> 8;
            int p = atomicAdd(&pos[cd_l], 1);
            csrc[p] = nb0 + cs_l;
            coef[p] = dv[cd_l] * dv[cs_l];
        }
    }
}

// ------- GCN aggregation (wave/node, 4 rows in flight) + fused score dot xs=h.Ws -------
__global__ void agg_gcn_k(const float* __restrict__ xw, const int* __restrict__ offs,
                          const int* __restrict__ offe, const int* __restrict__ csrc,
                          const float* __restrict__ coef, const float* __restrict__ dinv,
                          const float* __restrict__ bias, const float* __restrict__ Ws,
                          float* __restrict__ out, float* __restrict__ xs, int n) {
    int node = xcd_swz(blockIdx.x, gridDim.x) * 4 + (threadIdx.x >> 6);
    int lane = threadIdx.x & 63;
    const float4* xw4 = (const float4*)xw;
    float dd = dinv[node];
    float4 acc = {0.f, 0.f, 0.f, 0.f};
    int e0 = offs[node], e1 = offe[node];
    for (int j = e0; j < e1; j += 4) {
        int4   s4 = *(const int4*)&csrc[j];
        float4 c4 = *(const float4*)&coef[j];
        float4 v0 = xw4[(size_t)s4.x * 64 + lane];
        float4 v1 = xw4[(size_t)s4.y * 64 + lane];
        float4 v2 = xw4[(size_t)s4.z * 64 + lane];
        float4 v3 = xw4[(size_t)s4.w * 64 + lane];
        acc.x += c4.x * v0.x + c4.y * v1.x + c4.z * v2.x + c4.w * v3.x;
        acc.y += c4.x * v0.y + c4.y * v1.y + c4.z * v2.y + c4.w * v3.y;
        acc.z += c4.x * v0.z + c4.y * v1.z + c4.z * v2.z + c4.w * v3.z;
        acc.w += c4.x * v0.w + c4.y * v1.w + c4.z * v2.w + c4.w * v3.w;
    }
    float4 self = xw4[(size_t)node * 64 + lane];
    float scf = dd * dd;
    float4 r;
    r.x = fmaxf(acc.x + self.x * scf + bias[lane * 4 + 0], 0.f);
    r.y = fmaxf(acc.y + self.y * scf + bias[lane * 4 + 1], 0.f);
    r.z = fmaxf(acc.z + self.z * scf + bias[lane * 4 + 2], 0.f);
    r.w = fmaxf(acc.w + self.w * scf + bias[lane * 4 + 3], 0.f);
    ((float4*)out)[(size_t)node * 64 + lane] = r;
    float p = r.x * Ws[lane * 4 + 0] + r.y * Ws[lane * 4 + 1] +
              r.z * Ws[lane * 4 + 2] + r.w * Ws[lane * 4 + 3];
    #pragma unroll
    for (int d = 32; d > 0; d >>= 1) p += __shfl_down(p, d);
    if (lane == 0) xs[node] = p;
}

// -------- fused score GCN + top-k + pool + readout + CURMAP compose --------
__global__ void score_topk_pool_k(const float* __restrict__ h, const float* __restrict__ xs,
                                  const int* __restrict__ offs, const int* __restrict__ offe,
                                  const int* __restrict__ csrc, const float* __restrict__ coef,
                                  const float* __restrict__ dinv, const float* __restrict__ bs,
                                  int* __restrict__ curmap, float* __restrict__ ph,
                                  float* __restrict__ z, int npg, int k, int accumulate) {
    __shared__ float xsl[256];
    __shared__ float sc[256];
    __shared__ int   id[256];
    __shared__ int   rl[256];       // cur-local -> new cur-global (or -1)
    __shared__ int   ps[128];
    __shared__ float ts[128];
    int g = xcd_swz(blockIdx.x, B_);
    int t = threadIdx.x;
    int nb0 = g * npg;
    xsl[t] = (t < npg) ? xs[nb0 + t] : 0.f;
    rl[t] = -1;
    __syncthreads();
    float scv = -INFINITY;
    if (t < npg) {
        int gi = nb0 + t;
        float dd = dinv[gi];
        float acc = 0.f;
        for (int j = offs[gi]; j < offe[gi]; j++)
            acc += coef[j] * xsl[csrc[j] - nb0];
        scv = acc + xsl[t] * dd * dd + bs[0];
    }
    sc[t] = scv;
    id[t] = (t < npg) ? t : 0x7fffffff;
    __syncthreads();
    for (int ksz = 2; ksz <= 256; ksz <<= 1) {
        for (int j = ksz >> 1; j > 0; j >>= 1) {
            int ixj = t ^ j;
            if (ixj > t) {
                float s1 = sc[t], s2 = sc[ixj];
                int i1 = id[t], i2 = id[ixj];
                bool asc = ((t & ksz) == 0);
                bool agtb = (s1 < s2) || (s1 == s2 && i1 > i2);
                if (asc ? agtb : !agtb) { sc[t] = s2; sc[ixj] = s1; id[t] = i2; id[ixj] = i1; }
            }
            __syncthreads();
        }
    }
    if (t < k) {
        rl[id[t]] = g * k + t;
        ps[t] = nb0 + id[t];
        ts[t] = tanhf(sc[t]);
    }
    __syncthreads();
    // compose curmap: orig -> new cur id
    if (t < NPG_) {
        int o = g * NPG_ + t;
        int old = curmap[o];
        curmap[o] = (old < 0) ? -1 : rl[old - nb0];
    }
    // pool + readout: 256 threads = features
    float mx = -INFINITY, sm = 0.f;
    for (int j = 0; j < k; j++) {
        float v = h[(size_t)ps[j] * H_ + t] * ts[j];
        ph[(size_t)(g * k + j) * H_ + t] = v;
        mx = fmaxf(mx, v); sm += v;
    }
    float mean = sm / (float)k;
    if (accumulate) { z[g * 512 + t] += mx; z[g * 512 + 256 + t] += mean; }
    else            { z[g * 512 + t]  = mx; z[g * 512 + 256 + t]  = mean; }
}

// ---------------- fused MLP layer-3 + log_softmax ----------------
__global__ void mlp3_lsm_k(const float* __restrict__ A, const float* __restrict__ W,
                           const float* __restrict__ bias, float* __restrict__ out) {
    int m = blockIdx.x, l = threadIdx.x;   // 64 lanes, K=128
    float a0 = A[m * 128 + l], a1 = A[m * 128 + 64 + l];
    float r[10];
    #pragma unroll
    for (int n = 0; n < 10; n++) r[n] = a0 * W[l * 10 + n] + a1 * W[(l + 64) * 10 + n];
    #pragma unroll
    for (int d = 1; d < 64; d <<= 1)
        #pragma unroll
        for (int n = 0; n < 10; n++) r[n] += __shfl_xor(r[n], d);
    float v[10]; float mx = -INFINITY;
    #pragma unroll
    for (int n = 0; n < 10; n++) { v[n] = r[n] + bias[n]; mx = fmaxf(mx, v[n]); }
    float s = 0.f;
    #pragma unroll
    for (int n = 0; n < 10; n++) s += expf(v[n] - mx);
    float ls = logf(s);
    if (l < 10) out[m * 10 + l] = v[l] - mx - ls;
}

extern "C" void kernel_launch(void* const* d_in, const int* in_sizes, int n_in,
                              void* d_out, int out_size, void* d_ws, size_t ws_size,
                              hipStream_t stream) {
    const float* x   = (const float*)d_in[0];
    const int*  esrc = (const int*) d_in[1];
    const int*  edst = (const int*) d_in[2];
    const float *W1 = (const float*)d_in[3],  *b1 = (const float*)d_in[4];
    const float *Ws1= (const float*)d_in[5],  *bs1= (const float*)d_in[6];
    const float *W2 = (const float*)d_in[7],  *b2 = (const float*)d_in[8];
    const float *Ws2= (const float*)d_in[9],  *bs2= (const float*)d_in[10];
    const float *W3 = (const float*)d_in[11], *b3 = (const float*)d_in[12];
    const float *Ws3= (const float*)d_in[13], *bs3= (const float*)d_in[14];
    const float *Wl1= (const float*)d_in[15], *bl1= (const float*)d_in[16];
    const float *Wl2= (const float*)d_in[17], *bl2= (const float*)d_in[18];
    const float *Wl3= (const float*)d_in[19], *bl3= (const float*)d_in[20];
    float* out = (float*)d_out;

    // ---- workspace layout ----
    float* ws = (float*)d_ws;
    float* XW    = ws;                         // N0*H
    float* Hb    = XW + (size_t)N0_ * H_;      // N0*H
    float* PH    = Hb + (size_t)N0_ * H_;      // (B*K1)*H
    float* DINV  = PH + (size_t)B_ * K1_ * H_; // N0
    float* XS    = DINV + N0_;                 // N0
    int*   CURMAP= (int*)(XS + N0_);           // N0
    int*   OFFS  = CURMAP + N0_;               // N0
    int*   OFFE  = OFFS + N0_;                 // N0
    int*   CSRC  = OFFE + N0_;                 // CSRN
    float* COEF  = (float*)(CSRC + CSRN);      // CSRN
    float* Z     = COEF + CSRN;                // B*512
    float* Z1    = Z + B_ * 512;               // B*256
    float* Z2    = Z1 + B_ * 256;              // B*128

    init_curmap_k<<<N0_ / 256, 256, 0, stream>>>(CURMAP);

    const int npgs[3]  = { NPG_, K1_, K2_ };
    const int ks[3]    = { K1_, K2_, K3_ };
    const float* Wm[3]  = { W1, W2, W3 };
    const float* bm[3]  = { b1, b2, b3 };
    const float* Wsm[3] = { Ws1, Ws2, Ws3 };
    const float* bsm[3] = { bs1, bs2, bs3 };

    for (int st = 0; st < 3; st++) {
        int npg = npgs[st], k = ks[st];
        int n = B_ * npg;

        // 1. xw = X @ W
        if (st == 0)
            gemm_t<<<dim3(n / 64, H_ / 64), 256, 0, stream>>>(x, Wm[st], nullptr, XW, n, FIN_, H_, 0);
        else
            gemm_t<<<dim3(n / 64, H_ / 64), 256, 0, stream>>>(PH, Wm[st], nullptr, XW, n, H_, H_, 0);

        // 2. per-graph padded CSR build from original edges + CURMAP
        csr_build_k<<<B_, 256, 0, stream>>>(esrc, edst, CURMAP, OFFS, OFFE, CSRC, COEF, DINV, npg);

        // 3. h = relu(agg + self + b), fused xs = h.Ws
        agg_gcn_k<<<n / 4, 256, 0, stream>>>(XW, OFFS, OFFE, CSRC, COEF, DINV, bm[st], Wsm[st], Hb, XS, n);

        // 4-7. score GCN + top-k + pool + readout + CURMAP compose
        score_topk_pool_k<<<B_, 256, 0, stream>>>(Hb, XS, OFFS, OFFE, CSRC, COEF, DINV, bsm[st],
                                                  CURMAP, PH, Z, npg, k, st > 0 ? 1 : 0);
    }

    // ---- MLP head ----
    gemm_t<<<dim3(B_ / 64, 256 / 64), 256, 0, stream>>>(Z,  Wl1, bl1, Z1, B_, 512, 256, 1);
    gemm_t<<<dim3(B_ / 64, 128 / 64), 256, 0, stream>>>(Z1, Wl2, bl2, Z2, B_, 256, 128, 1);
    mlp3_lsm_k<<<B_, 64, 0, stream>>>(Z2, Wl3, bl3, out);
}